// Round 10
// baseline (490.912 us; speedup 1.0000x reference)
//
#include <hip/hip_runtime.h>
#include <hip/hip_bf16.h>
#include <math.h>

#define NN 20000
#define EE 640000
#define NB 157      // buckets of 128 dst nodes
#define BCAP 5120   // per-bucket capacity (mean 4076 + 16 sigma)
#define NBLK 160    // binning blocks per type
#define CHNK 4000   // edges per binning block

typedef float v2f __attribute__((ext_vector_type(2)));

__device__ __forceinline__ void wave_fence() {
  __builtin_amdgcn_wave_barrier();
  asm volatile("s_waitcnt lgkmcnt(0)" ::: "memory");
  __builtin_amdgcn_wave_barrier();
}

__device__ __forceinline__ unsigned pack_bf2(float a, float b) {
  __hip_bfloat162 h2 = __float22bfloat162_rn(make_float2(a, b));
  return *(unsigned*)&h2;
}
__device__ __forceinline__ float2 unpack_bf2(unsigned v) {
  float2 r;
  unsigned lo = v << 16, hi = v & 0xffff0000u;
  r.x = __uint_as_float(lo);
  r.y = __uint_as_float(hi);
  return r;
}

// ---------------- CSR build pass 1: bin edges by dst>>7 (grid-strided, packed) ----------------
__global__ __launch_bounds__(256) void bin_k(const int* __restrict__ ea,
                                             const int* __restrict__ eb,
                                             int* __restrict__ gcnt,
                                             int* __restrict__ bbuf) {
  int t = blockIdx.y;
  const int* ei = t ? eb : ea;
  int tid = threadIdx.x;
  __shared__ int lh[NB], lbase[NB];
  if (tid < NB) lh[tid] = 0;
  __syncthreads();
  int e0 = blockIdx.x * CHNK;
  int e1 = min(e0 + CHNK, EE);
  int myb[16], myr[16], myv[16];
#pragma unroll
  for (int i = 0; i < 16; ++i) {
    int e = e0 + tid + i * 256;
    if (e < e1) {
      int s = ei[e], d = ei[EE + e];
      int b = d >> 7;
      myb[i] = b;
      myv[i] = (s << 7) | (d & 127);
      myr[i] = atomicAdd(&lh[b], 1);
    } else {
      myb[i] = -1;
    }
  }
  __syncthreads();
  if (tid < NB) {
    int c = lh[tid];
    lbase[tid] = c ? atomicAdd(&gcnt[t * NB + tid], c) : 0;
  }
  __syncthreads();
#pragma unroll
  for (int i = 0; i < 16; ++i) {
    int b = myb[i];
    if (b >= 0) {
      int pos = lbase[b] + myr[i];
      if (pos < BCAP) bbuf[((size_t)t * NB + b) * BCAP + pos] = myv[i];
    }
  }
}

// ---------------- CSR build pass 2a: parallel segmented scan of bucket counts ----------------
__global__ __launch_bounds__(512) void bscan_k(const int* __restrict__ gcnt,
                                               int* __restrict__ bstart) {
  __shared__ int buf[512];
  int tid = threadIdx.x;
  int t = tid >> 8, b = tid & 255;
  int val = (b < NB) ? gcnt[t * NB + b] : 0;
  buf[tid] = val;
  __syncthreads();
  for (int s = 1; s < 256; s <<= 1) {
    int x = ((tid & 255) >= s) ? buf[tid - s] : 0;
    __syncthreads();
    buf[tid] += x;
    __syncthreads();
  }
  if (b < NB) bstart[t * NB + b] = buf[tid] - val;
}

// ---------------- CSR build pass 2b: per-bucket local counting sort ----------------
__global__ __launch_bounds__(256) void build_k(const int* __restrict__ gcnt,
                                               const int* __restrict__ bstart,
                                               const int* __restrict__ bbuf,
                                               int* __restrict__ rowptr,
                                               int* __restrict__ csr) {
  int b = blockIdx.x, t = blockIdx.y;
  int cnt = gcnt[t * NB + b];
  int start = bstart[t * NB + b];
  int n0 = b << 7;
  int nlocal = min(128, NN - n0);
  int tid = threadIdx.x;
  __shared__ int arr[128], lcur[128];
  if (tid < 128) arr[tid] = 0;
  __syncthreads();
  const int* ebuf = bbuf + ((size_t)t * NB + b) * BCAP;
  for (int i = tid; i < cnt; i += 256) atomicAdd(&arr[ebuf[i] & 127], 1);
  __syncthreads();
  int deg = (tid < 128) ? arr[tid] : 0;
  for (int s = 1; s < 128; s <<= 1) {
    int x = (tid < 128 && tid >= s) ? arr[tid - s] : 0;
    __syncthreads();
    if (tid < 128) arr[tid] += x;
    __syncthreads();
  }
  if (tid < nlocal) {
    int incl = arr[tid];
    rowptr[t * (NN + 1) + n0 + tid + 1] = start + incl;
    lcur[tid] = start + incl - deg;
  }
  if (b == 0 && tid == 0) rowptr[t * (NN + 1)] = 0;
  __syncthreads();
  for (int i = tid; i < cnt; i += 256) {
    int v = ebuf[i];
    int pos = atomicAdd(&lcur[v & 127], 1);
    csr[(size_t)t * EE + pos] = v >> 7;
  }
}

// ---------------- fp32 tiled GEMM with optional bf16-packed secondary output ----------------
template <int NT, int BM, int BN, int BK, int TM, int TN>
__global__ __launch_bounds__(NT) void sgemm_k(const float* __restrict__ A,
                                              const float* __restrict__ B,
                                              float* __restrict__ C, int M, int N, int K,
                                              long long Abs, long long Bbs, long long Cbs,
                                              unsigned* __restrict__ Cb, long long Cbb) {
  A += blockIdx.z * Abs; B += blockIdx.z * Bbs; C += blockIdx.z * Cbs;
  if (Cb) Cb += blockIdx.z * Cbb;
  const int bm = blockIdx.x * BM, bn = blockIdx.y * BN;
  __shared__ float As[BK][BM + 4];
  __shared__ float Bs[BK][BN + 4];
  int tid = threadIdx.x;
  constexpr int TX = BN / TN;
  int tx = tid % TX, ty = tid / TX;
  float acc[TM][TN] = {};
  for (int k0 = 0; k0 < K; k0 += BK) {
#pragma unroll
    for (int i = 0; i < (BM * BK) / (NT * 4); ++i) {
      int idx = tid + i * NT;
      int row = idx / (BK / 4), kq = idx % (BK / 4);
      float4 v = make_float4(0.f, 0.f, 0.f, 0.f);
      int gr = bm + row;
      if (gr < M) v = *(const float4*)&A[(size_t)gr * K + k0 + kq * 4];
      As[kq * 4 + 0][row] = v.x; As[kq * 4 + 1][row] = v.y;
      As[kq * 4 + 2][row] = v.z; As[kq * 4 + 3][row] = v.w;
    }
#pragma unroll
    for (int i = 0; i < (BK * BN) / (NT * 4); ++i) {
      int idx = tid + i * NT;
      int row = idx / (BN / 4), cq = idx % (BN / 4);
      *(float4*)&Bs[row][cq * 4] = *(const float4*)&B[(size_t)(k0 + row) * N + bn + cq * 4];
    }
    __syncthreads();
#pragma unroll
    for (int k = 0; k < BK; ++k) {
      float a[TM], b[TN];
#pragma unroll
      for (int i = 0; i < TM; i += 4) *(float4*)&a[i] = *(float4*)&As[k][ty * TM + i];
#pragma unroll
      for (int j = 0; j < TN; j += 4) *(float4*)&b[j] = *(float4*)&Bs[k][tx * TN + j];
#pragma unroll
      for (int i = 0; i < TM; ++i)
#pragma unroll
        for (int j = 0; j < TN; ++j) acc[i][j] += a[i] * b[j];
    }
    __syncthreads();
  }
#pragma unroll
  for (int i = 0; i < TM; ++i) {
    int gr = bm + ty * TM + i;
    if (gr < M) {
#pragma unroll
      for (int j = 0; j < TN; j += 4)
        *(float4*)&C[(size_t)gr * N + bn + tx * TN + j] = *(float4*)&acc[i][j];
      if (Cb) {
#pragma unroll
        for (int j = 0; j < TN; j += 2)
          Cb[(size_t)gr * (N >> 1) + ((bn + tx * TN + j) >> 1)] = pack_bf2(acc[i][j], acc[i][j + 1]);
      }
    }
  }
}

// ---------------- split-K GEMM, packed-bf16 A: P[t][kc][M,64] ----------------
template <int NT, int BM, int BK, int TM, int TN, int KC>
__global__ __launch_bounds__(NT) void sgemm_splitk_k(const unsigned* __restrict__ Ap,
                                                     const float* __restrict__ B,
                                                     float* __restrict__ P, int M, int K) {
  const int N = 64;
  int t = blockIdx.z;
  Ap += (size_t)t * M * (K >> 1);
  B += (size_t)t * 65536;
  P += ((size_t)t * 4 + blockIdx.y) * M * N;
  const int bm = blockIdx.x * BM;
  const int k0base = blockIdx.y * KC;
  __shared__ float As[BK][BM + 4];
  __shared__ float Bs[BK][N + 4];
  int tid = threadIdx.x;
  constexpr int TX = N / TN;
  int tx = tid % TX, ty = tid / TX;
  float acc[TM][TN] = {};
  for (int k0 = k0base; k0 < k0base + KC; k0 += BK) {
    {
      int row = tid >> 2, q = tid & 3;
      int gr = bm + row;
      uint4 u = make_uint4(0u, 0u, 0u, 0u);
      if (gr < M) u = *(const uint4*)&Ap[(size_t)gr * (K >> 1) + (k0 >> 1) + q * 4];
      float2 f0 = unpack_bf2(u.x), f1 = unpack_bf2(u.y);
      float2 f2 = unpack_bf2(u.z), f3 = unpack_bf2(u.w);
      int kl = q * 8;
      As[kl + 0][row] = f0.x; As[kl + 1][row] = f0.y;
      As[kl + 2][row] = f1.x; As[kl + 3][row] = f1.y;
      As[kl + 4][row] = f2.x; As[kl + 5][row] = f2.y;
      As[kl + 6][row] = f3.x; As[kl + 7][row] = f3.y;
    }
#pragma unroll
    for (int i = 0; i < (BK * N) / (NT * 4); ++i) {
      int idx = tid + i * NT;
      int row = idx / (N / 4), cq = idx % (N / 4);
      *(float4*)&Bs[row][cq * 4] = *(const float4*)&B[(size_t)(k0 + row) * N + cq * 4];
    }
    __syncthreads();
#pragma unroll
    for (int k = 0; k < BK; ++k) {
      float a[TM], b[TN];
#pragma unroll
      for (int i = 0; i < TM; i += 4) *(float4*)&a[i] = *(float4*)&As[k][ty * TM + i];
#pragma unroll
      for (int j = 0; j < TN; j += 4) *(float4*)&b[j] = *(float4*)&Bs[k][tx * TN + j];
#pragma unroll
      for (int i = 0; i < TM; ++i)
#pragma unroll
        for (int j = 0; j < TN; ++j) acc[i][j] += a[i] * b[j];
    }
    __syncthreads();
  }
#pragma unroll
  for (int i = 0; i < TM; ++i) {
    int gr = bm + ty * TM + i;
    if (gr < M) {
#pragma unroll
      for (int j = 0; j < TN; j += 4)
        *(float4*)&P[(size_t)gr * N + tx * TN + j] = *(float4*)&acc[i][j];
    }
  }
}

// ---------------- layer-1 attention scores from h1 ----------------
template <int C>
__global__ void score_k(const float* __restrict__ hf, const float* __restrict__ as_,
                        const float* __restrict__ ad_, float* __restrict__ ss,
                        float* __restrict__ sd) {
  int idx = blockIdx.x * 256 + threadIdx.x;
  if (idx >= 2 * NN * 8) return;
  int t = idx / (NN * 8), r = idx % (NN * 8), n = r / 8, hh = r % 8;
  const int HC = 8 * C;
  const float* hrow = hf + (size_t)t * NN * HC + (size_t)n * HC + hh * C;
  const float* a1 = as_ + t * HC + hh * C;
  const float* a2 = ad_ + t * HC + hh * C;
  float s1 = 0.f, s2 = 0.f;
#pragma unroll
  for (int c = 0; c < C; c += 4) {
    float4 f = *(const float4*)&hrow[c];
    float4 u = *(const float4*)&a1[c];
    float4 w = *(const float4*)&a2[c];
    s1 += f.x * u.x + f.y * u.y + f.z * u.z + f.w * u.w;
    s2 += f.x * w.x + f.y * w.y + f.z * w.z + f.w * w.w;
  }
  ss[idx] = s1; sd[idx] = s2;
}

__device__ __forceinline__ float lrelu(float v) { return v > 0.f ? v : 0.2f * v; }

// ---------------- layer-1 aggregation: wave per node, bf16 gather, pk-fma ----------------
__global__ __launch_bounds__(256) void aggw1_k(const int* __restrict__ rowptr,
                                               const int* __restrict__ csr,
                                               const float* __restrict__ ssrc,
                                               const float* __restrict__ sdst,
                                               const unsigned* __restrict__ hb,
                                               float* __restrict__ out) {
  int t = blockIdx.y;
  rowptr += t * (NN + 1); csr += (size_t)t * EE;
  ssrc += (size_t)t * NN * 8; sdst += (size_t)t * NN * 8;
  hb += (size_t)t * NN * 64; out += (size_t)t * NN * 128;
  int tid = threadIdx.x, w = tid >> 6, lane = tid & 63;
  int n = blockIdx.x * 4 + w;
  int row = rowptr[n], end = rowptr[n + 1];
  __shared__ int sidx[4][64];
  __shared__ float sexp[4][64][8];
  float4 sda = *(const float4*)&sdst[(size_t)n * 8];
  float4 sdb = *(const float4*)&sdst[(size_t)n * 8 + 4];
  float za_x = 0.f, za_y = 0.f, za_z = 0.f, za_w = 0.f;
  float zb_x = 0.f, zb_y = 0.f, zb_z = 0.f, zb_w = 0.f;
  int hme = lane >> 3;
  v2f acc = {0.f, 0.f};
  for (int base = row; base < end; base += 64) {
    int cnt = min(64, end - base);
    if (lane < cnt) {
      int s = csr[base + lane];
      sidx[w][lane] = s;
      float4 pa = *(const float4*)&ssrc[(size_t)s * 8];
      float4 pb = *(const float4*)&ssrc[(size_t)s * 8 + 4];
      float4 ea, eb;
      ea.x = __expf(lrelu(pa.x + sda.x)); ea.y = __expf(lrelu(pa.y + sda.y));
      ea.z = __expf(lrelu(pa.z + sda.z)); ea.w = __expf(lrelu(pa.w + sda.w));
      eb.x = __expf(lrelu(pb.x + sdb.x)); eb.y = __expf(lrelu(pb.y + sdb.y));
      eb.z = __expf(lrelu(pb.z + sdb.z)); eb.w = __expf(lrelu(pb.w + sdb.w));
      za_x += ea.x; za_y += ea.y; za_z += ea.z; za_w += ea.w;
      zb_x += eb.x; zb_y += eb.y; zb_z += eb.z; zb_w += eb.w;
      *(float4*)&sexp[w][lane][0] = ea;
      *(float4*)&sexp[w][lane][4] = eb;
    }
    wave_fence();
    for (int e = 0; e < cnt; ++e) {
      int s = __builtin_amdgcn_readfirstlane(sidx[w][e]);
      const unsigned* hp = hb + (size_t)s * 64;   // scalar base -> SALU addressing
      float a = sexp[w][e][hme];
      float2 vf = unpack_bf2(hp[lane]);
      v2f v = {vf.x, vf.y};
      acc += a * v;
    }
    wave_fence();
  }
#pragma unroll
  for (int off = 32; off; off >>= 1) {
    za_x += __shfl_xor(za_x, off); za_y += __shfl_xor(za_y, off);
    za_z += __shfl_xor(za_z, off); za_w += __shfl_xor(za_w, off);
    zb_x += __shfl_xor(zb_x, off); zb_y += __shfl_xor(zb_y, off);
    zb_z += __shfl_xor(zb_z, off); zb_w += __shfl_xor(zb_w, off);
  }
  float zh[8] = {za_x, za_y, za_z, za_w, zb_x, zb_y, zb_z, zb_w};
  float z = zh[hme];
  float iz = z > 0.f ? 1.f / z : 0.f;
  *(float2*)&out[(size_t)n * 128 + lane * 2] = make_float2(acc.x * iz, acc.y * iz);
}

// ---------------- hetero-mean + bias + ELU (layer 1), writes fp32 + packed bf16 ----------------
__global__ void combine1_k(const float* __restrict__ oa, const float* __restrict__ ob,
                           const float* __restrict__ b1, float* __restrict__ hmid,
                           unsigned* __restrict__ hmidb) {
  int idx = blockIdx.x * 256 + threadIdx.x;
  if (idx >= NN * 64) return;
  int n = idx >> 6, j2 = idx & 63, j = j2 * 2;
  float2 va = *(const float2*)&oa[(size_t)n * 128 + j];
  float2 vb = *(const float2*)&ob[(size_t)n * 128 + j];
  float vx = 0.5f * ((va.x + b1[j]) + (vb.x + b1[128 + j]));
  float vy = 0.5f * ((va.y + b1[j + 1]) + (vb.y + b1[128 + j + 1]));
  vx = vx > 0.f ? vx : (__expf(vx) - 1.f);
  vy = vy > 0.f ? vy : (__expf(vy) - 1.f);
  *(float2*)&hmid[(size_t)n * 128 + j] = make_float2(vx, vy);
  hmidb[idx] = pack_bf2(vx, vy);
}

// ---------------- layer-2 folds ----------------
__global__ void fold2_k(const float* __restrict__ W2, const float* __restrict__ a2s,
                        const float* __restrict__ a2d, float* __restrict__ wsf,
                        float* __restrict__ wdf) {
  int idx = blockIdx.x * 256 + threadIdx.x;
  if (idx >= 2048) return;
  int t = idx >> 10, r = idx & 1023, hh = r >> 7, k = r & 127;
  const float* wrow = W2 + (size_t)t * 65536 + (size_t)k * 512 + hh * 64;
  const float* as = a2s + t * 512 + hh * 64;
  const float* ad = a2d + t * 512 + hh * 64;
  float s1 = 0.f, s2 = 0.f;
  for (int c = 0; c < 64; ++c) { s1 += wrow[c] * as[c]; s2 += wrow[c] * ad[c]; }
  wsf[idx] = s1; wdf[idx] = s2;
}

__global__ void foldB_k(const float* __restrict__ W2, float* __restrict__ Bmat) {
  int idx = blockIdx.x * 256 + threadIdx.x;
  if (idx >= 131072) return;
  int t = idx >> 16, r = idx & 65535, rowr = r >> 6, c = r & 63;
  int hh = rowr >> 7, k = rowr & 127;
  Bmat[idx] = 0.125f * W2[(size_t)t * 65536 + (size_t)k * 512 + hh * 64 + c];
}

// ---------------- layer-2 scores from hmid ----------------
__global__ void score2_k(const float* __restrict__ hmid, const float* __restrict__ wsf,
                         const float* __restrict__ wdf, float* __restrict__ ss,
                         float* __restrict__ sdo) {
  int idx = blockIdx.x * 256 + threadIdx.x;
  if (idx >= NN * 8) return;
  int n = idx >> 3, hh = idx & 7;
  const float* hm = hmid + (size_t)n * 128;
  const float* w0s = wsf + (size_t)hh * 128;
  const float* w0d = wdf + (size_t)hh * 128;
  const float* w1s = wsf + (size_t)(8 + hh) * 128;
  const float* w1d = wdf + (size_t)(8 + hh) * 128;
  float s0s = 0.f, s0d = 0.f, s1s = 0.f, s1d = 0.f;
#pragma unroll
  for (int c = 0; c < 128; c += 4) {
    float4 f = *(const float4*)&hm[c];
    float4 a = *(const float4*)&w0s[c];
    float4 b = *(const float4*)&w0d[c];
    float4 u = *(const float4*)&w1s[c];
    float4 v = *(const float4*)&w1d[c];
    s0s += f.x * a.x + f.y * a.y + f.z * a.z + f.w * a.w;
    s0d += f.x * b.x + f.y * b.y + f.z * b.z + f.w * b.w;
    s1s += f.x * u.x + f.y * u.y + f.z * u.z + f.w * u.w;
    s1d += f.x * v.x + f.y * v.y + f.z * v.z + f.w * v.w;
  }
  ss[idx] = s0s; sdo[idx] = s0d;
  ss[NN * 8 + idx] = s1s; sdo[NN * 8 + idx] = s1d;
}

// ---------------- layer-2 aggregation: wave per node, both types, pk-fma, bf16 in/out ----------------
__global__ __launch_bounds__(256) void aggw2_k(const int* __restrict__ rowptr,
                                               const int* __restrict__ csr,
                                               const float* __restrict__ ssrc,
                                               const float* __restrict__ sdst,
                                               const unsigned* __restrict__ hmidb,
                                               unsigned* __restrict__ aggp) {
  int t = blockIdx.y;
  rowptr += t * (NN + 1); csr += (size_t)t * EE;
  ssrc += (size_t)t * NN * 8; sdst += (size_t)t * NN * 8;
  aggp += (size_t)t * NN * 512;
  int tid = threadIdx.x, w = tid >> 6, lane = tid & 63;
  int n = blockIdx.x * 4 + w;
  int row = rowptr[n], end = rowptr[n + 1];
  __shared__ int sidx[4][64];
  __shared__ float sexp[4][64][8];
  float4 sda = *(const float4*)&sdst[(size_t)n * 8];
  float4 sdb = *(const float4*)&sdst[(size_t)n * 8 + 4];
  float za_x = 0.f, za_y = 0.f, za_z = 0.f, za_w = 0.f;
  float zb_x = 0.f, zb_y = 0.f, zb_z = 0.f, zb_w = 0.f;
  v2f acc[8];
#pragma unroll
  for (int i = 0; i < 8; ++i) acc[i] = (v2f){0.f, 0.f};
  for (int base = row; base < end; base += 64) {
    int cnt = min(64, end - base);
    if (lane < cnt) {
      int s = csr[base + lane];
      sidx[w][lane] = s;
      float4 pa = *(const float4*)&ssrc[(size_t)s * 8];
      float4 pb = *(const float4*)&ssrc[(size_t)s * 8 + 4];
      float4 ea, eb;
      ea.x = __expf(lrelu(pa.x + sda.x)); ea.y = __expf(lrelu(pa.y + sda.y));
      ea.z = __expf(lrelu(pa.z + sda.z)); ea.w = __expf(lrelu(pa.w + sda.w));
      eb.x = __expf(lrelu(pb.x + sdb.x)); eb.y = __expf(lrelu(pb.y + sdb.y));
      eb.z = __expf(lrelu(pb.z + sdb.z)); eb.w = __expf(lrelu(pb.w + sdb.w));
      za_x += ea.x; za_y += ea.y; za_z += ea.z; za_w += ea.w;
      zb_x += eb.x; zb_y += eb.y; zb_z += eb.z; zb_w += eb.w;
      *(float4*)&sexp[w][lane][0] = ea;
      *(float4*)&sexp[w][lane][4] = eb;
    }
    wave_fence();
    for (int e = 0; e < cnt; ++e) {
      int s = __builtin_amdgcn_readfirstlane(sidx[w][e]);
      const unsigned* hp = hmidb + (size_t)s * 64;   // scalar base -> SALU addressing
      unsigned uv = hp[lane];
      float4 ea = *(const float4*)&sexp[w][e][0];
      float4 eb = *(const float4*)&sexp[w][e][4];
      float2 vf = unpack_bf2(uv);
      v2f v = {vf.x, vf.y};
      acc[0] += ea.x * v;
      acc[1] += ea.y * v;
      acc[2] += ea.z * v;
      acc[3] += ea.w * v;
      acc[4] += eb.x * v;
      acc[5] += eb.y * v;
      acc[6] += eb.z * v;
      acc[7] += eb.w * v;
    }
    wave_fence();
  }
#pragma unroll
  for (int off = 32; off; off >>= 1) {
    za_x += __shfl_xor(za_x, off); za_y += __shfl_xor(za_y, off);
    za_z += __shfl_xor(za_z, off); za_w += __shfl_xor(za_w, off);
    zb_x += __shfl_xor(zb_x, off); zb_y += __shfl_xor(zb_y, off);
    zb_z += __shfl_xor(zb_z, off); zb_w += __shfl_xor(zb_w, off);
  }
  float zh[8] = {za_x, za_y, za_z, za_w, zb_x, zb_y, zb_z, zb_w};
#pragma unroll
  for (int i = 0; i < 8; ++i) {
    float z = zh[i];
    float iz = z > 0.f ? 1.f / z : 0.f;
    aggp[(size_t)n * 512 + i * 64 + lane] = pack_bf2(acc[i].x * iz, acc[i].y * iz);
  }
}

// ---------------- reduce split-K partials + hetero-mean + bias + ELU (layer 2) ----------------
__global__ void combine2p_k(const float* __restrict__ P, const float* __restrict__ b2,
                            float* __restrict__ feat) {
  int idx = blockIdx.x * 256 + threadIdx.x;
  if (idx >= NN * 16) return;
  int n = idx >> 4, j = (idx & 15) * 4;
  const size_t SZ = (size_t)NN * 64;
  size_t o = (size_t)n * 64 + j;
  float4 sa = make_float4(0.f, 0.f, 0.f, 0.f), sb = sa;
#pragma unroll
  for (int k = 0; k < 4; ++k) {
    float4 va = *(const float4*)&P[k * SZ + o];
    float4 vb = *(const float4*)&P[(4 + k) * SZ + o];
    sa.x += va.x; sa.y += va.y; sa.z += va.z; sa.w += va.w;
    sb.x += vb.x; sb.y += vb.y; sb.z += vb.z; sb.w += vb.w;
  }
  float4 ba = *(const float4*)&b2[j];
  float4 bb = *(const float4*)&b2[64 + j];
  float4 v;
  v.x = 0.5f * ((sa.x + ba.x) + (sb.x + bb.x));
  v.y = 0.5f * ((sa.y + ba.y) + (sb.y + bb.y));
  v.z = 0.5f * ((sa.z + ba.z) + (sb.z + bb.z));
  v.w = 0.5f * ((sa.w + ba.w) + (sb.w + bb.w));
  v.x = v.x > 0.f ? v.x : (__expf(v.x) - 1.f);
  v.y = v.y > 0.f ? v.y : (__expf(v.y) - 1.f);
  v.z = v.z > 0.f ? v.z : (__expf(v.z) - 1.f);
  v.w = v.w > 0.f ? v.w : (__expf(v.w) - 1.f);
  *(float4*)&feat[o] = v;
}

// ---------------- classifier ----------------
__global__ __launch_bounds__(256) void cls_k(const float* __restrict__ feat,
                                             const float* __restrict__ Wc1,
                                             const float* __restrict__ bc1,
                                             const float* __restrict__ Wc2,
                                             const float* __restrict__ bc2,
                                             float* __restrict__ out) {
  __shared__ float w1[64 * 32];
  __shared__ float w2[64];
  __shared__ float b1s[32], b2s[2];
  __shared__ float fs[8 * 64];
  __shared__ float hs[8 * 32];
  int tid = threadIdx.x;
  for (int i = tid; i < 2048; i += 256) w1[i] = Wc1[i];
  if (tid < 64) w2[tid] = Wc2[tid];
  if (tid < 32) b1s[tid] = bc1[tid];
  if (tid < 2) b2s[tid] = bc2[tid];
  int nbase = blockIdx.x * 8;
  for (int i = tid; i < 512; i += 256) fs[i] = feat[(size_t)nbase * 64 + i];
  __syncthreads();
  int local = tid >> 5, tt = tid & 31;
  const float* f = fs + local * 64;
  float acc = b1s[tt];
#pragma unroll
  for (int c = 0; c < 64; ++c) acc += f[c] * w1[c * 32 + tt];
  hs[local * 32 + tt] = fmaxf(acc, 0.f);
  __syncthreads();
  if (tid < 16) {
    int l = tid >> 1, j = tid & 1;
    float o = b2s[j];
#pragma unroll
    for (int i = 0; i < 32; ++i) o += hs[l * 32 + i] * w2[i * 2 + j];
    out[(size_t)(nbase + l) * 2 + j] = o;
  }
}

extern "C" void kernel_launch(void* const* d_in, const int* in_sizes, int n_in,
                              void* d_out, int out_size, void* d_ws, size_t ws_size,
                              hipStream_t stream) {
  const float* x   = (const float*)d_in[0];
  const int* eia   = (const int*)d_in[1];
  const int* eib   = (const int*)d_in[2];
  const float* W1  = (const float*)d_in[3];
  const float* a1s = (const float*)d_in[4];
  const float* a1d = (const float*)d_in[5];
  const float* b1  = (const float*)d_in[6];
  const float* W2  = (const float*)d_in[7];
  const float* a2s = (const float*)d_in[8];
  const float* a2d = (const float*)d_in[9];
  const float* b2  = (const float*)d_in[10];
  const float* Wc1 = (const float*)d_in[11];
  const float* bc1 = (const float*)d_in[12];
  const float* Wc2 = (const float*)d_in[13];
  const float* bc2 = (const float*)d_in[14];
  float* out = (float*)d_out;

  char* ws = (char*)d_ws;
  size_t off = 0;
  auto alloc = [&](size_t bytes) -> char* {
    char* p = ws + off;
    off += (bytes + 255) & ~(size_t)255;
    return p;
  };
  int* gcnt       = (int*)alloc((size_t)2 * NB * 4);
  int* bstart     = (int*)alloc((size_t)2 * NB * 4);
  int* bbuf       = (int*)alloc((size_t)2 * NB * BCAP * 4);
  int* rowptr     = (int*)alloc((size_t)2 * (NN + 1) * 4);
  int* csr        = (int*)alloc((size_t)2 * EE * 4);
  float* h1       = (float*)alloc((size_t)2 * NN * 128 * 4);
  unsigned* h1b   = (unsigned*)alloc((size_t)2 * NN * 64 * 4);
  float* s1s      = (float*)alloc((size_t)2 * NN * 8 * 4);
  float* s1d      = (float*)alloc((size_t)2 * NN * 8 * 4);
  float* o1       = (float*)alloc((size_t)2 * NN * 128 * 4);
  float* hmid     = (float*)alloc((size_t)NN * 128 * 4);
  unsigned* hmidb = (unsigned*)alloc((size_t)NN * 64 * 4);
  float* wsf      = (float*)alloc((size_t)2048 * 4);
  float* wdf      = (float*)alloc((size_t)2048 * 4);
  float* Bmat     = (float*)alloc((size_t)131072 * 4);
  float* s2s      = (float*)alloc((size_t)2 * NN * 8 * 4);
  float* s2d      = (float*)alloc((size_t)2 * NN * 8 * 4);
  unsigned* aggp  = (unsigned*)alloc((size_t)2 * NN * 512 * 4);  // bf16-packed agg, both types
  float* pbuf     = (float*)alloc((size_t)8 * NN * 64 * 4);      // split-K partials
  float* feat     = (float*)alloc((size_t)NN * 64 * 4);

  // CSR build: bucketed two-pass (grid-strided binning, packed entries)
  hipMemsetAsync(gcnt, 0, (size_t)2 * NB * 4, stream);
  bin_k<<<dim3(NBLK, 2), 256, 0, stream>>>(eia, eib, gcnt, bbuf);
  bscan_k<<<1, 512, 0, stream>>>(gcnt, bstart);
  build_k<<<dim3(NB, 2), 256, 0, stream>>>(gcnt, bstart, bbuf, rowptr, csr);

  // layer-2 weight folds (independent of layer 1; launch early)
  fold2_k<<<8, 256, 0, stream>>>(W2, a2s, a2d, wsf, wdf);
  foldB_k<<<512, 256, 0, stream>>>(W2, Bmat);

  // layer 1 (GEMM writes fp32 h1 + packed bf16 h1b in epilogue)
  sgemm_k<256, 64, 64, 32, 4, 4><<<dim3((NN + 63) / 64, 2, 2), 256, 0, stream>>>(
      x, W1, h1, NN, 128, 256, 0LL, 256LL * 128, (long long)NN * 128, h1b, (long long)NN * 64);
  score_k<16><<<(2 * NN * 8 + 255) / 256, 256, 0, stream>>>(h1, a1s, a1d, s1s, s1d);
  aggw1_k<<<dim3(NN / 4, 2), 256, 0, stream>>>(rowptr, csr, s1s, s1d, h1b, o1);
  combine1_k<<<(NN * 64 + 255) / 256, 256, 0, stream>>>(o1, o1 + (size_t)NN * 128, b1, hmid, hmidb);

  // layer 2: scores, merged both-type aggregation (bf16 out), merged split-K GEMM
  score2_k<<<(NN * 8 + 255) / 256, 256, 0, stream>>>(hmid, wsf, wdf, s2s, s2d);
  aggw2_k<<<dim3(NN / 4, 2), 256, 0, stream>>>(rowptr, csr, s2s, s2d, hmidb, aggp);
  sgemm_splitk_k<256, 64, 32, 4, 4, 256><<<dim3((NN + 63) / 64, 4, 2), 256, 0, stream>>>(
      aggp, Bmat, pbuf, NN, 1024);
  combine2p_k<<<(NN * 16 + 255) / 256, 256, 0, stream>>>(pbuf, b2, feat);

  // classifier
  cls_k<<<NN / 8, 256, 0, stream>>>(feat, Wc1, bc1, Wc2, bc2, out);
}

// Round 11
// 447.109 us; speedup vs baseline: 1.0980x; 1.0980x over previous
//
#include <hip/hip_runtime.h>
#include <hip/hip_bf16.h>
#include <math.h>

#define NN 20000
#define EE 640000
#define NB 157      // buckets of 128 dst nodes
#define BCAP 5120   // per-bucket capacity (mean 4076 + 16 sigma)
#define NBLK 160    // binning blocks per type
#define CHNK 4000   // edges per binning block

typedef float v2f __attribute__((ext_vector_type(2)));

__device__ __forceinline__ void wave_fence() {
  __builtin_amdgcn_wave_barrier();
  asm volatile("s_waitcnt lgkmcnt(0)" ::: "memory");
  __builtin_amdgcn_wave_barrier();
}

__device__ __forceinline__ unsigned pack_bf2(float a, float b) {
  __hip_bfloat162 h2 = __float22bfloat162_rn(make_float2(a, b));
  return *(unsigned*)&h2;
}
__device__ __forceinline__ float2 unpack_bf2(unsigned v) {
  float2 r;
  unsigned lo = v << 16, hi = v & 0xffff0000u;
  r.x = __uint_as_float(lo);
  r.y = __uint_as_float(hi);
  return r;
}

// ---------------- CSR build pass 1: bin edges by dst>>7 (grid-strided, packed) ----------------
__global__ __launch_bounds__(256) void bin_k(const int* __restrict__ ea,
                                             const int* __restrict__ eb,
                                             int* __restrict__ gcnt,
                                             int* __restrict__ bbuf) {
  int t = blockIdx.y;
  const int* ei = t ? eb : ea;
  int tid = threadIdx.x;
  __shared__ int lh[NB], lbase[NB];
  if (tid < NB) lh[tid] = 0;
  __syncthreads();
  int e0 = blockIdx.x * CHNK;
  int e1 = min(e0 + CHNK, EE);
  int myb[16], myr[16], myv[16];
#pragma unroll
  for (int i = 0; i < 16; ++i) {
    int e = e0 + tid + i * 256;
    if (e < e1) {
      int s = ei[e], d = ei[EE + e];
      int b = d >> 7;
      myb[i] = b;
      myv[i] = (s << 7) | (d & 127);
      myr[i] = atomicAdd(&lh[b], 1);
    } else {
      myb[i] = -1;
    }
  }
  __syncthreads();
  if (tid < NB) {
    int c = lh[tid];
    lbase[tid] = c ? atomicAdd(&gcnt[t * NB + tid], c) : 0;
  }
  __syncthreads();
#pragma unroll
  for (int i = 0; i < 16; ++i) {
    int b = myb[i];
    if (b >= 0) {
      int pos = lbase[b] + myr[i];
      if (pos < BCAP) bbuf[((size_t)t * NB + b) * BCAP + pos] = myv[i];
    }
  }
}

// ---------------- CSR build pass 2a: parallel segmented scan of bucket counts ----------------
__global__ __launch_bounds__(512) void bscan_k(const int* __restrict__ gcnt,
                                               int* __restrict__ bstart) {
  __shared__ int buf[512];
  int tid = threadIdx.x;
  int t = tid >> 8, b = tid & 255;
  int val = (b < NB) ? gcnt[t * NB + b] : 0;
  buf[tid] = val;
  __syncthreads();
  for (int s = 1; s < 256; s <<= 1) {
    int x = ((tid & 255) >= s) ? buf[tid - s] : 0;
    __syncthreads();
    buf[tid] += x;
    __syncthreads();
  }
  if (b < NB) bstart[t * NB + b] = buf[tid] - val;
}

// ---------------- CSR build pass 2b: per-bucket local counting sort ----------------
__global__ __launch_bounds__(256) void build_k(const int* __restrict__ gcnt,
                                               const int* __restrict__ bstart,
                                               const int* __restrict__ bbuf,
                                               int* __restrict__ rowptr,
                                               int* __restrict__ csr) {
  int b = blockIdx.x, t = blockIdx.y;
  int cnt = gcnt[t * NB + b];
  int start = bstart[t * NB + b];
  int n0 = b << 7;
  int nlocal = min(128, NN - n0);
  int tid = threadIdx.x;
  __shared__ int arr[128], lcur[128];
  if (tid < 128) arr[tid] = 0;
  __syncthreads();
  const int* ebuf = bbuf + ((size_t)t * NB + b) * BCAP;
  for (int i = tid; i < cnt; i += 256) atomicAdd(&arr[ebuf[i] & 127], 1);
  __syncthreads();
  int deg = (tid < 128) ? arr[tid] : 0;
  for (int s = 1; s < 128; s <<= 1) {
    int x = (tid < 128 && tid >= s) ? arr[tid - s] : 0;
    __syncthreads();
    if (tid < 128) arr[tid] += x;
    __syncthreads();
  }
  if (tid < nlocal) {
    int incl = arr[tid];
    rowptr[t * (NN + 1) + n0 + tid + 1] = start + incl;
    lcur[tid] = start + incl - deg;
  }
  if (b == 0 && tid == 0) rowptr[t * (NN + 1)] = 0;
  __syncthreads();
  for (int i = tid; i < cnt; i += 256) {
    int v = ebuf[i];
    int pos = atomicAdd(&lcur[v & 127], 1);
    csr[(size_t)t * EE + pos] = v >> 7;
  }
}

// ---------------- fp32 tiled GEMM with optional bf16-packed secondary output ----------------
template <int NT, int BM, int BN, int BK, int TM, int TN>
__global__ __launch_bounds__(NT) void sgemm_k(const float* __restrict__ A,
                                              const float* __restrict__ B,
                                              float* __restrict__ C, int M, int N, int K,
                                              long long Abs, long long Bbs, long long Cbs,
                                              unsigned* __restrict__ Cb, long long Cbb) {
  A += blockIdx.z * Abs; B += blockIdx.z * Bbs; C += blockIdx.z * Cbs;
  if (Cb) Cb += blockIdx.z * Cbb;
  const int bm = blockIdx.x * BM, bn = blockIdx.y * BN;
  __shared__ float As[BK][BM + 4];
  __shared__ float Bs[BK][BN + 4];
  int tid = threadIdx.x;
  constexpr int TX = BN / TN;
  int tx = tid % TX, ty = tid / TX;
  float acc[TM][TN] = {};
  for (int k0 = 0; k0 < K; k0 += BK) {
#pragma unroll
    for (int i = 0; i < (BM * BK) / (NT * 4); ++i) {
      int idx = tid + i * NT;
      int row = idx / (BK / 4), kq = idx % (BK / 4);
      float4 v = make_float4(0.f, 0.f, 0.f, 0.f);
      int gr = bm + row;
      if (gr < M) v = *(const float4*)&A[(size_t)gr * K + k0 + kq * 4];
      As[kq * 4 + 0][row] = v.x; As[kq * 4 + 1][row] = v.y;
      As[kq * 4 + 2][row] = v.z; As[kq * 4 + 3][row] = v.w;
    }
#pragma unroll
    for (int i = 0; i < (BK * BN) / (NT * 4); ++i) {
      int idx = tid + i * NT;
      int row = idx / (BN / 4), cq = idx % (BN / 4);
      *(float4*)&Bs[row][cq * 4] = *(const float4*)&B[(size_t)(k0 + row) * N + bn + cq * 4];
    }
    __syncthreads();
#pragma unroll
    for (int k = 0; k < BK; ++k) {
      float a[TM], b[TN];
#pragma unroll
      for (int i = 0; i < TM; i += 4) *(float4*)&a[i] = *(float4*)&As[k][ty * TM + i];
#pragma unroll
      for (int j = 0; j < TN; j += 4) *(float4*)&b[j] = *(float4*)&Bs[k][tx * TN + j];
#pragma unroll
      for (int i = 0; i < TM; ++i)
#pragma unroll
        for (int j = 0; j < TN; ++j) acc[i][j] += a[i] * b[j];
    }
    __syncthreads();
  }
#pragma unroll
  for (int i = 0; i < TM; ++i) {
    int gr = bm + ty * TM + i;
    if (gr < M) {
#pragma unroll
      for (int j = 0; j < TN; j += 4)
        *(float4*)&C[(size_t)gr * N + bn + tx * TN + j] = *(float4*)&acc[i][j];
      if (Cb) {
#pragma unroll
        for (int j = 0; j < TN; j += 2)
          Cb[(size_t)gr * (N >> 1) + ((bn + tx * TN + j) >> 1)] = pack_bf2(acc[i][j], acc[i][j + 1]);
      }
    }
  }
}

// ---------------- split-K GEMM, packed-bf16 A: P[t][kc][M,64] ----------------
template <int NT, int BM, int BK, int TM, int TN, int KC>
__global__ __launch_bounds__(NT) void sgemm_splitk_k(const unsigned* __restrict__ Ap,
                                                     const float* __restrict__ B,
                                                     float* __restrict__ P, int M, int K) {
  const int N = 64;
  int t = blockIdx.z;
  Ap += (size_t)t * M * (K >> 1);
  B += (size_t)t * 65536;
  P += ((size_t)t * 4 + blockIdx.y) * M * N;
  const int bm = blockIdx.x * BM;
  const int k0base = blockIdx.y * KC;
  __shared__ float As[BK][BM + 4];
  __shared__ float Bs[BK][N + 4];
  int tid = threadIdx.x;
  constexpr int TX = N / TN;
  int tx = tid % TX, ty = tid / TX;
  float acc[TM][TN] = {};
  for (int k0 = k0base; k0 < k0base + KC; k0 += BK) {
    {
      int row = tid >> 2, q = tid & 3;
      int gr = bm + row;
      uint4 u = make_uint4(0u, 0u, 0u, 0u);
      if (gr < M) u = *(const uint4*)&Ap[(size_t)gr * (K >> 1) + (k0 >> 1) + q * 4];
      float2 f0 = unpack_bf2(u.x), f1 = unpack_bf2(u.y);
      float2 f2 = unpack_bf2(u.z), f3 = unpack_bf2(u.w);
      int kl = q * 8;
      As[kl + 0][row] = f0.x; As[kl + 1][row] = f0.y;
      As[kl + 2][row] = f1.x; As[kl + 3][row] = f1.y;
      As[kl + 4][row] = f2.x; As[kl + 5][row] = f2.y;
      As[kl + 6][row] = f3.x; As[kl + 7][row] = f3.y;
    }
#pragma unroll
    for (int i = 0; i < (BK * N) / (NT * 4); ++i) {
      int idx = tid + i * NT;
      int row = idx / (N / 4), cq = idx % (N / 4);
      *(float4*)&Bs[row][cq * 4] = *(const float4*)&B[(size_t)(k0 + row) * N + cq * 4];
    }
    __syncthreads();
#pragma unroll
    for (int k = 0; k < BK; ++k) {
      float a[TM], b[TN];
#pragma unroll
      for (int i = 0; i < TM; i += 4) *(float4*)&a[i] = *(float4*)&As[k][ty * TM + i];
#pragma unroll
      for (int j = 0; j < TN; j += 4) *(float4*)&b[j] = *(float4*)&Bs[k][tx * TN + j];
#pragma unroll
      for (int i = 0; i < TM; ++i)
#pragma unroll
        for (int j = 0; j < TN; ++j) acc[i][j] += a[i] * b[j];
    }
    __syncthreads();
  }
#pragma unroll
  for (int i = 0; i < TM; ++i) {
    int gr = bm + ty * TM + i;
    if (gr < M) {
#pragma unroll
      for (int j = 0; j < TN; j += 4)
        *(float4*)&P[(size_t)gr * N + tx * TN + j] = *(float4*)&acc[i][j];
    }
  }
}

// ---------------- layer-1 attention scores from h1 ----------------
template <int C>
__global__ void score_k(const float* __restrict__ hf, const float* __restrict__ as_,
                        const float* __restrict__ ad_, float* __restrict__ ss,
                        float* __restrict__ sd) {
  int idx = blockIdx.x * 256 + threadIdx.x;
  if (idx >= 2 * NN * 8) return;
  int t = idx / (NN * 8), r = idx % (NN * 8), n = r / 8, hh = r % 8;
  const int HC = 8 * C;
  const float* hrow = hf + (size_t)t * NN * HC + (size_t)n * HC + hh * C;
  const float* a1 = as_ + t * HC + hh * C;
  const float* a2 = ad_ + t * HC + hh * C;
  float s1 = 0.f, s2 = 0.f;
#pragma unroll
  for (int c = 0; c < C; c += 4) {
    float4 f = *(const float4*)&hrow[c];
    float4 u = *(const float4*)&a1[c];
    float4 w = *(const float4*)&a2[c];
    s1 += f.x * u.x + f.y * u.y + f.z * u.z + f.w * u.w;
    s2 += f.x * w.x + f.y * w.y + f.z * w.z + f.w * w.w;
  }
  ss[idx] = s1; sd[idx] = s2;
}

__device__ __forceinline__ float lrelu(float v) { return v > 0.f ? v : 0.2f * v; }

// ---------------- layer-1 aggregation: wave per node, bf16 gather, pk acc ----------------
__global__ __launch_bounds__(256) void aggw1_k(const int* __restrict__ rowptr,
                                               const int* __restrict__ csr,
                                               const float* __restrict__ ssrc,
                                               const float* __restrict__ sdst,
                                               const unsigned* __restrict__ hb,
                                               float* __restrict__ out) {
  int t = blockIdx.y;
  rowptr += t * (NN + 1); csr += (size_t)t * EE;
  ssrc += (size_t)t * NN * 8; sdst += (size_t)t * NN * 8;
  hb += (size_t)t * NN * 64; out += (size_t)t * NN * 128;
  int tid = threadIdx.x, w = tid >> 6, lane = tid & 63;
  int n = blockIdx.x * 4 + w;
  int row = rowptr[n], end = rowptr[n + 1];
  __shared__ int sidx[4][64];
  __shared__ float sexp[4][64][8];
  float4 sda = *(const float4*)&sdst[(size_t)n * 8];
  float4 sdb = *(const float4*)&sdst[(size_t)n * 8 + 4];
  float za_x = 0.f, za_y = 0.f, za_z = 0.f, za_w = 0.f;
  float zb_x = 0.f, zb_y = 0.f, zb_z = 0.f, zb_w = 0.f;
  int hme = lane >> 3;
  v2f acc = {0.f, 0.f};
  for (int base = row; base < end; base += 64) {
    int cnt = min(64, end - base);
    if (lane < cnt) {
      int s = csr[base + lane];
      sidx[w][lane] = s;
      float4 pa = *(const float4*)&ssrc[(size_t)s * 8];
      float4 pb = *(const float4*)&ssrc[(size_t)s * 8 + 4];
      float4 ea, eb;
      ea.x = __expf(lrelu(pa.x + sda.x)); ea.y = __expf(lrelu(pa.y + sda.y));
      ea.z = __expf(lrelu(pa.z + sda.z)); ea.w = __expf(lrelu(pa.w + sda.w));
      eb.x = __expf(lrelu(pb.x + sdb.x)); eb.y = __expf(lrelu(pb.y + sdb.y));
      eb.z = __expf(lrelu(pb.z + sdb.z)); eb.w = __expf(lrelu(pb.w + sdb.w));
      za_x += ea.x; za_y += ea.y; za_z += ea.z; za_w += ea.w;
      zb_x += eb.x; zb_y += eb.y; zb_z += eb.z; zb_w += eb.w;
      *(float4*)&sexp[w][lane][0] = ea;
      *(float4*)&sexp[w][lane][4] = eb;
    }
    wave_fence();
    for (int e = 0; e < cnt; ++e) {
      int s = sidx[w][e];                 // VGPR address path (pipelinable)
      float a = sexp[w][e][hme];
      float2 vf = unpack_bf2(hb[(size_t)s * 64 + lane]);
      v2f v = {vf.x, vf.y};
      acc += a * v;
    }
    wave_fence();
  }
#pragma unroll
  for (int off = 32; off; off >>= 1) {
    za_x += __shfl_xor(za_x, off); za_y += __shfl_xor(za_y, off);
    za_z += __shfl_xor(za_z, off); za_w += __shfl_xor(za_w, off);
    zb_x += __shfl_xor(zb_x, off); zb_y += __shfl_xor(zb_y, off);
    zb_z += __shfl_xor(zb_z, off); zb_w += __shfl_xor(zb_w, off);
  }
  float zh[8] = {za_x, za_y, za_z, za_w, zb_x, zb_y, zb_z, zb_w};
  float z = zh[hme];
  float iz = z > 0.f ? 1.f / z : 0.f;
  *(float2*)&out[(size_t)n * 128 + lane * 2] = make_float2(acc.x * iz, acc.y * iz);
}

// ---------------- hetero-mean + bias + ELU (layer 1), writes fp32 + packed bf16 ----------------
__global__ void combine1_k(const float* __restrict__ oa, const float* __restrict__ ob,
                           const float* __restrict__ b1, float* __restrict__ hmid,
                           unsigned* __restrict__ hmidb) {
  int idx = blockIdx.x * 256 + threadIdx.x;
  if (idx >= NN * 64) return;
  int n = idx >> 6, j2 = idx & 63, j = j2 * 2;
  float2 va = *(const float2*)&oa[(size_t)n * 128 + j];
  float2 vb = *(const float2*)&ob[(size_t)n * 128 + j];
  float vx = 0.5f * ((va.x + b1[j]) + (vb.x + b1[128 + j]));
  float vy = 0.5f * ((va.y + b1[j + 1]) + (vb.y + b1[128 + j + 1]));
  vx = vx > 0.f ? vx : (__expf(vx) - 1.f);
  vy = vy > 0.f ? vy : (__expf(vy) - 1.f);
  *(float2*)&hmid[(size_t)n * 128 + j] = make_float2(vx, vy);
  hmidb[idx] = pack_bf2(vx, vy);
}

// ---------------- layer-2 folds ----------------
__global__ void fold2_k(const float* __restrict__ W2, const float* __restrict__ a2s,
                        const float* __restrict__ a2d, float* __restrict__ wsf,
                        float* __restrict__ wdf) {
  int idx = blockIdx.x * 256 + threadIdx.x;
  if (idx >= 2048) return;
  int t = idx >> 10, r = idx & 1023, hh = r >> 7, k = r & 127;
  const float* wrow = W2 + (size_t)t * 65536 + (size_t)k * 512 + hh * 64;
  const float* as = a2s + t * 512 + hh * 64;
  const float* ad = a2d + t * 512 + hh * 64;
  float s1 = 0.f, s2 = 0.f;
  for (int c = 0; c < 64; ++c) { s1 += wrow[c] * as[c]; s2 += wrow[c] * ad[c]; }
  wsf[idx] = s1; wdf[idx] = s2;
}

__global__ void foldB_k(const float* __restrict__ W2, float* __restrict__ Bmat) {
  int idx = blockIdx.x * 256 + threadIdx.x;
  if (idx >= 131072) return;
  int t = idx >> 16, r = idx & 65535, rowr = r >> 6, c = r & 63;
  int hh = rowr >> 7, k = rowr & 127;
  Bmat[idx] = 0.125f * W2[(size_t)t * 65536 + (size_t)k * 512 + hh * 64 + c];
}

// ---------------- layer-2 scores from hmid ----------------
__global__ void score2_k(const float* __restrict__ hmid, const float* __restrict__ wsf,
                         const float* __restrict__ wdf, float* __restrict__ ss,
                         float* __restrict__ sdo) {
  int idx = blockIdx.x * 256 + threadIdx.x;
  if (idx >= NN * 8) return;
  int n = idx >> 3, hh = idx & 7;
  const float* hm = hmid + (size_t)n * 128;
  const float* w0s = wsf + (size_t)hh * 128;
  const float* w0d = wdf + (size_t)hh * 128;
  const float* w1s = wsf + (size_t)(8 + hh) * 128;
  const float* w1d = wdf + (size_t)(8 + hh) * 128;
  float s0s = 0.f, s0d = 0.f, s1s = 0.f, s1d = 0.f;
#pragma unroll
  for (int c = 0; c < 128; c += 4) {
    float4 f = *(const float4*)&hm[c];
    float4 a = *(const float4*)&w0s[c];
    float4 b = *(const float4*)&w0d[c];
    float4 u = *(const float4*)&w1s[c];
    float4 v = *(const float4*)&w1d[c];
    s0s += f.x * a.x + f.y * a.y + f.z * a.z + f.w * a.w;
    s0d += f.x * b.x + f.y * b.y + f.z * b.z + f.w * b.w;
    s1s += f.x * u.x + f.y * u.y + f.z * u.z + f.w * u.w;
    s1d += f.x * v.x + f.y * v.y + f.z * v.z + f.w * v.w;
  }
  ss[idx] = s0s; sdo[idx] = s0d;
  ss[NN * 8 + idx] = s1s; sdo[NN * 8 + idx] = s1d;
}

// ---------------- layer-2 aggregation: wave per node, both types, pk acc, bf16 in/out ----------------
__global__ __launch_bounds__(256) void aggw2_k(const int* __restrict__ rowptr,
                                               const int* __restrict__ csr,
                                               const float* __restrict__ ssrc,
                                               const float* __restrict__ sdst,
                                               const unsigned* __restrict__ hmidb,
                                               unsigned* __restrict__ aggp) {
  int t = blockIdx.y;
  rowptr += t * (NN + 1); csr += (size_t)t * EE;
  ssrc += (size_t)t * NN * 8; sdst += (size_t)t * NN * 8;
  aggp += (size_t)t * NN * 512;
  int tid = threadIdx.x, w = tid >> 6, lane = tid & 63;
  int n = blockIdx.x * 4 + w;
  int row = rowptr[n], end = rowptr[n + 1];
  __shared__ int sidx[4][64];
  __shared__ float sexp[4][64][8];
  float4 sda = *(const float4*)&sdst[(size_t)n * 8];
  float4 sdb = *(const float4*)&sdst[(size_t)n * 8 + 4];
  float za_x = 0.f, za_y = 0.f, za_z = 0.f, za_w = 0.f;
  float zb_x = 0.f, zb_y = 0.f, zb_z = 0.f, zb_w = 0.f;
  v2f acc[8];
#pragma unroll
  for (int i = 0; i < 8; ++i) acc[i] = (v2f){0.f, 0.f};
  for (int base = row; base < end; base += 64) {
    int cnt = min(64, end - base);
    if (lane < cnt) {
      int s = csr[base + lane];
      sidx[w][lane] = s;
      float4 pa = *(const float4*)&ssrc[(size_t)s * 8];
      float4 pb = *(const float4*)&ssrc[(size_t)s * 8 + 4];
      float4 ea, eb;
      ea.x = __expf(lrelu(pa.x + sda.x)); ea.y = __expf(lrelu(pa.y + sda.y));
      ea.z = __expf(lrelu(pa.z + sda.z)); ea.w = __expf(lrelu(pa.w + sda.w));
      eb.x = __expf(lrelu(pb.x + sdb.x)); eb.y = __expf(lrelu(pb.y + sdb.y));
      eb.z = __expf(lrelu(pb.z + sdb.z)); eb.w = __expf(lrelu(pb.w + sdb.w));
      za_x += ea.x; za_y += ea.y; za_z += ea.z; za_w += ea.w;
      zb_x += eb.x; zb_y += eb.y; zb_z += eb.z; zb_w += eb.w;
      *(float4*)&sexp[w][lane][0] = ea;
      *(float4*)&sexp[w][lane][4] = eb;
    }
    wave_fence();
    for (int e = 0; e < cnt; ++e) {
      int s = sidx[w][e];                 // VGPR address path (pipelinable)
      unsigned uv = hmidb[(size_t)s * 64 + lane];
      float4 ea = *(const float4*)&sexp[w][e][0];
      float4 eb = *(const float4*)&sexp[w][e][4];
      float2 vf = unpack_bf2(uv);
      v2f v = {vf.x, vf.y};
      acc[0] += ea.x * v;
      acc[1] += ea.y * v;
      acc[2] += ea.z * v;
      acc[3] += ea.w * v;
      acc[4] += eb.x * v;
      acc[5] += eb.y * v;
      acc[6] += eb.z * v;
      acc[7] += eb.w * v;
    }
    wave_fence();
  }
#pragma unroll
  for (int off = 32; off; off >>= 1) {
    za_x += __shfl_xor(za_x, off); za_y += __shfl_xor(za_y, off);
    za_z += __shfl_xor(za_z, off); za_w += __shfl_xor(za_w, off);
    zb_x += __shfl_xor(zb_x, off); zb_y += __shfl_xor(zb_y, off);
    zb_z += __shfl_xor(zb_z, off); zb_w += __shfl_xor(zb_w, off);
  }
  float zh[8] = {za_x, za_y, za_z, za_w, zb_x, zb_y, zb_z, zb_w};
#pragma unroll
  for (int i = 0; i < 8; ++i) {
    float z = zh[i];
    float iz = z > 0.f ? 1.f / z : 0.f;
    aggp[(size_t)n * 512 + i * 64 + lane] = pack_bf2(acc[i].x * iz, acc[i].y * iz);
  }
}

// ---------------- reduce split-K partials + hetero-mean + bias + ELU (layer 2) ----------------
__global__ void combine2p_k(const float* __restrict__ P, const float* __restrict__ b2,
                            float* __restrict__ feat) {
  int idx = blockIdx.x * 256 + threadIdx.x;
  if (idx >= NN * 16) return;
  int n = idx >> 4, j = (idx & 15) * 4;
  const size_t SZ = (size_t)NN * 64;
  size_t o = (size_t)n * 64 + j;
  float4 sa = make_float4(0.f, 0.f, 0.f, 0.f), sb = sa;
#pragma unroll
  for (int k = 0; k < 4; ++k) {
    float4 va = *(const float4*)&P[k * SZ + o];
    float4 vb = *(const float4*)&P[(4 + k) * SZ + o];
    sa.x += va.x; sa.y += va.y; sa.z += va.z; sa.w += va.w;
    sb.x += vb.x; sb.y += vb.y; sb.z += vb.z; sb.w += vb.w;
  }
  float4 ba = *(const float4*)&b2[j];
  float4 bb = *(const float4*)&b2[64 + j];
  float4 v;
  v.x = 0.5f * ((sa.x + ba.x) + (sb.x + bb.x));
  v.y = 0.5f * ((sa.y + ba.y) + (sb.y + bb.y));
  v.z = 0.5f * ((sa.z + ba.z) + (sb.z + bb.z));
  v.w = 0.5f * ((sa.w + ba.w) + (sb.w + bb.w));
  v.x = v.x > 0.f ? v.x : (__expf(v.x) - 1.f);
  v.y = v.y > 0.f ? v.y : (__expf(v.y) - 1.f);
  v.z = v.z > 0.f ? v.z : (__expf(v.z) - 1.f);
  v.w = v.w > 0.f ? v.w : (__expf(v.w) - 1.f);
  *(float4*)&feat[o] = v;
}

// ---------------- classifier ----------------
__global__ __launch_bounds__(256) void cls_k(const float* __restrict__ feat,
                                             const float* __restrict__ Wc1,
                                             const float* __restrict__ bc1,
                                             const float* __restrict__ Wc2,
                                             const float* __restrict__ bc2,
                                             float* __restrict__ out) {
  __shared__ float w1[64 * 32];
  __shared__ float w2[64];
  __shared__ float b1s[32], b2s[2];
  __shared__ float fs[8 * 64];
  __shared__ float hs[8 * 32];
  int tid = threadIdx.x;
  for (int i = tid; i < 2048; i += 256) w1[i] = Wc1[i];
  if (tid < 64) w2[tid] = Wc2[tid];
  if (tid < 32) b1s[tid] = bc1[tid];
  if (tid < 2) b2s[tid] = bc2[tid];
  int nbase = blockIdx.x * 8;
  for (int i = tid; i < 512; i += 256) fs[i] = feat[(size_t)nbase * 64 + i];
  __syncthreads();
  int local = tid >> 5, tt = tid & 31;
  const float* f = fs + local * 64;
  float acc = b1s[tt];
#pragma unroll
  for (int c = 0; c < 64; ++c) acc += f[c] * w1[c * 32 + tt];
  hs[local * 32 + tt] = fmaxf(acc, 0.f);
  __syncthreads();
  if (tid < 16) {
    int l = tid >> 1, j = tid & 1;
    float o = b2s[j];
#pragma unroll
    for (int i = 0; i < 32; ++i) o += hs[l * 32 + i] * w2[i * 2 + j];
    out[(size_t)(nbase + l) * 2 + j] = o;
  }
}

extern "C" void kernel_launch(void* const* d_in, const int* in_sizes, int n_in,
                              void* d_out, int out_size, void* d_ws, size_t ws_size,
                              hipStream_t stream) {
  const float* x   = (const float*)d_in[0];
  const int* eia   = (const int*)d_in[1];
  const int* eib   = (const int*)d_in[2];
  const float* W1  = (const float*)d_in[3];
  const float* a1s = (const float*)d_in[4];
  const float* a1d = (const float*)d_in[5];
  const float* b1  = (const float*)d_in[6];
  const float* W2  = (const float*)d_in[7];
  const float* a2s = (const float*)d_in[8];
  const float* a2d = (const float*)d_in[9];
  const float* b2  = (const float*)d_in[10];
  const float* Wc1 = (const float*)d_in[11];
  const float* bc1 = (const float*)d_in[12];
  const float* Wc2 = (const float*)d_in[13];
  const float* bc2 = (const float*)d_in[14];
  float* out = (float*)d_out;

  char* ws = (char*)d_ws;
  size_t off = 0;
  auto alloc = [&](size_t bytes) -> char* {
    char* p = ws + off;
    off += (bytes + 255) & ~(size_t)255;
    return p;
  };
  int* gcnt       = (int*)alloc((size_t)2 * NB * 4);
  int* bstart     = (int*)alloc((size_t)2 * NB * 4);
  int* bbuf       = (int*)alloc((size_t)2 * NB * BCAP * 4);
  int* rowptr     = (int*)alloc((size_t)2 * (NN + 1) * 4);
  int* csr        = (int*)alloc((size_t)2 * EE * 4);
  float* h1       = (float*)alloc((size_t)2 * NN * 128 * 4);
  unsigned* h1b   = (unsigned*)alloc((size_t)2 * NN * 64 * 4);
  float* s1s      = (float*)alloc((size_t)2 * NN * 8 * 4);
  float* s1d      = (float*)alloc((size_t)2 * NN * 8 * 4);
  float* o1       = (float*)alloc((size_t)2 * NN * 128 * 4);
  float* hmid     = (float*)alloc((size_t)NN * 128 * 4);
  unsigned* hmidb = (unsigned*)alloc((size_t)NN * 64 * 4);
  float* wsf      = (float*)alloc((size_t)2048 * 4);
  float* wdf      = (float*)alloc((size_t)2048 * 4);
  float* Bmat     = (float*)alloc((size_t)131072 * 4);
  float* s2s      = (float*)alloc((size_t)2 * NN * 8 * 4);
  float* s2d      = (float*)alloc((size_t)2 * NN * 8 * 4);
  unsigned* aggp  = (unsigned*)alloc((size_t)2 * NN * 512 * 4);  // bf16-packed agg, both types
  float* pbuf     = (float*)alloc((size_t)8 * NN * 64 * 4);      // split-K partials
  float* feat     = (float*)alloc((size_t)NN * 64 * 4);

  // CSR build: bucketed two-pass (grid-strided binning, packed entries)
  hipMemsetAsync(gcnt, 0, (size_t)2 * NB * 4, stream);
  bin_k<<<dim3(NBLK, 2), 256, 0, stream>>>(eia, eib, gcnt, bbuf);
  bscan_k<<<1, 512, 0, stream>>>(gcnt, bstart);
  build_k<<<dim3(NB, 2), 256, 0, stream>>>(gcnt, bstart, bbuf, rowptr, csr);

  // layer-2 weight folds (independent of layer 1; launch early)
  fold2_k<<<8, 256, 0, stream>>>(W2, a2s, a2d, wsf, wdf);
  foldB_k<<<512, 256, 0, stream>>>(W2, Bmat);

  // layer 1 (GEMM writes fp32 h1 + packed bf16 h1b in epilogue)
  sgemm_k<256, 64, 64, 32, 4, 4><<<dim3((NN + 63) / 64, 2, 2), 256, 0, stream>>>(
      x, W1, h1, NN, 128, 256, 0LL, 256LL * 128, (long long)NN * 128, h1b, (long long)NN * 64);
  score_k<16><<<(2 * NN * 8 + 255) / 256, 256, 0, stream>>>(h1, a1s, a1d, s1s, s1d);
  aggw1_k<<<dim3(NN / 4, 2), 256, 0, stream>>>(rowptr, csr, s1s, s1d, h1b, o1);
  combine1_k<<<(NN * 64 + 255) / 256, 256, 0, stream>>>(o1, o1 + (size_t)NN * 128, b1, hmid, hmidb);

  // layer 2: scores, merged both-type aggregation (bf16 out), merged split-K GEMM
  score2_k<<<(NN * 8 + 255) / 256, 256, 0, stream>>>(hmid, wsf, wdf, s2s, s2d);
  aggw2_k<<<dim3(NN / 4, 2), 256, 0, stream>>>(rowptr, csr, s2s, s2d, hmidb, aggp);
  sgemm_splitk_k<256, 64, 32, 4, 4, 256><<<dim3((NN + 63) / 64, 4, 2), 256, 0, stream>>>(
      aggp, Bmat, pbuf, NN, 1024);
  combine2p_k<<<(NN * 16 + 255) / 256, 256, 0, stream>>>(pbuf, b2, feat);

  // classifier
  cls_k<<<NN / 8, 256, 0, stream>>>(feat, Wc1, bc1, Wc2, bc2, out);
}